// Round 6
// baseline (85.824 us; speedup 1.0000x reference)
//
#include <hip/hip_runtime.h>

#define ROWF 84        // floats per output row (80 cls + 4 reg)
#define RSTRIDE 17     // 32-bit words per LDS row-block (odd => conflict-free)
// row-block layout (words): 0-3 hitmask | 4-6 graymask | 7 px | 8 py
//                           | 9 inv_half | 10-13 reg float4 bits

// One block = one wave = 64 consecutive points of one image (levels are
// 64-aligned -> wave is level-uniform; P = 341*64, no tail).
// Every output byte is written EXACTLY ONCE by a coalesced float4 store:
// no atomics, no vmcnt fences, no re-touched lines. Wave lifetime = compute.
//  phase 0: preload gts -> LDS, classify size, ballot-compact (ascending g)
//  phase 1: 4-chain branchless min-score scan over ALL gts (argmin fallback)
//  phase 2: heavy loop over compacted gts: hit test; green -> set bit i in
//           per-row hitmask + track best; gray -> label bitmask
//  phase 3: owner writes its 68 B row-block to LDS
//  phase 4: writeback: 21 iters; j=k*64+tid -> row j/21, slot j%21; ~21
//           lanes share a row (broadcast LDS reads); reconstruct 4 class
//           values from hit bits (recomputed scores, cndmask max), apply
//           gray -1, store out4[j]. Stores fire-and-forget.
__global__ __launch_bounds__(64) void lfd_kernel(
    const float* __restrict__ gt_bboxes,   // (B,G,4) x0,y0,w,h
    const int*   __restrict__ gt_labels,   // (B,G)
    const float* __restrict__ points,      // (P,2)
    const float* __restrict__ reg_ranges,  // (P,2)
    const float* __restrict__ gray_ranges, // (P,2)
    const float* __restrict__ strides,     // (P,)
    float* __restrict__ out,               // (B,P,84)
    int G, int P)
{
    extern __shared__ float lds[];
    float4*   boxA  = (float4*)lds;                      // [G] x0,y0,x1m1,y1m1
    float2*   ctr   = (float2*)(boxA + G);               // [G] cx,cy
    unsigned* clist = (unsigned*)(ctr + ((G + 1) & ~1)); // [G] compacted
    unsigned* rowd  = clist + G;                         // [64*RSTRIDE]

    const int tid = threadIdx.x;
    const int b   = blockIdx.y;
    const int p   = blockIdx.x * 64 + tid;

    // --- per-point (wave-uniform level) constants ---
    const float px  = points[p * 2 + 0];
    const float py  = points[p * 2 + 1];
    const float lo  = reg_ranges[p * 2 + 0];
    const float up  = reg_ranges[p * 2 + 1];
    const float glo = gray_ranges[p * 2 + 0];
    const float gup = gray_ranges[p * 2 + 1];
    const float inv_half = 2.0f / strides[p];  // strides pow2 -> exact
    const float inv_up   = 1.0f / up;

    // --- phase 0: preload gts (slots g=tid, g=tid+64), classify ---
    bool i0 = false, gray0 = false, i1 = false, gray1 = false;
    int  lab0 = 0, lab1 = 0;
    {
        int g = tid;
        if (g < G) {
            const float4 bb = *(const float4*)(gt_bboxes + (size_t)(b * G + g) * 4);
            boxA[g] = make_float4(bb.x, bb.y, bb.x + bb.z - 1.0f, bb.y + bb.w - 1.0f);
            ctr[g]  = make_float2(bb.x + 0.5f * bb.z, bb.y + 0.5f * bb.w);
            const float larger = fmaxf(bb.z, bb.w);
            lab0 = gt_labels[b * G + g];
            const bool green = (lo <= larger) && (larger <= up);
            gray0 = ((glo <= larger) && (larger < lo)) || ((up < larger) && (larger <= gup));
            i0 = green || gray0;
        }
        g = tid + 64;
        if (g < G) {
            const float4 bb = *(const float4*)(gt_bboxes + (size_t)(b * G + g) * 4);
            boxA[g] = make_float4(bb.x, bb.y, bb.x + bb.z - 1.0f, bb.y + bb.w - 1.0f);
            ctr[g]  = make_float2(bb.x + 0.5f * bb.z, bb.y + 0.5f * bb.w);
            const float larger = fmaxf(bb.z, bb.w);
            lab1 = gt_labels[b * G + g];
            const bool green = (lo <= larger) && (larger <= up);
            gray1 = ((glo <= larger) && (larger < lo)) || ((up < larger) && (larger <= gup));
            i1 = green || gray1;
        }
    }
    const unsigned long long m0 = __ballot(i0);
    const unsigned long long m1 = __ballot(i1);
    const int c0 = __popcll(m0);
    const unsigned long long below = (1ull << tid) - 1ull;
    if (i0) clist[__popcll(m0 & below)] =
        (unsigned)tid | ((unsigned)lab0 << 8) | (gray0 ? 0x80000000u : 0u);
    if (i1) clist[c0 + __popcll(m1 & below)] =
        (unsigned)(tid + 64) | ((unsigned)lab1 << 8) | (gray1 ? 0x80000000u : 0u);
    const int ncomp = c0 + __popcll(m1);

    // --- phase 1: 4-chain branchless min-score scan (argmin fallback) ---
#define SC(X, Y) rsqrtf(fmaxf(fabsf(px - (X)) * inv_half, 1.0f) * \
                        fmaxf(fabsf(py - (Y)) * inv_half, 1.0f))
    const float4* ctr2 = (const float4*)ctr;
    float ms0 = 1e30f, ms1 = 1e30f, ms2 = 1e30f, ms3 = 1e30f;
    int   mg0 = 0, mg1 = 0, mg2 = 0, mg3 = 0;
    int g = 0;
    for (; g + 8 <= G; g += 8) {
        const float4 ca = ctr2[(g >> 1) + 0];
        const float4 cb = ctr2[(g >> 1) + 1];
        const float4 cc = ctr2[(g >> 1) + 2];
        const float4 cd = ctr2[(g >> 1) + 3];
        float s;
        s = SC(ca.x, ca.y); if (s < ms0) { ms0 = s; mg0 = g + 0; }
        s = SC(ca.z, ca.w); if (s < ms0) { ms0 = s; mg0 = g + 1; }
        s = SC(cb.x, cb.y); if (s < ms1) { ms1 = s; mg1 = g + 2; }
        s = SC(cb.z, cb.w); if (s < ms1) { ms1 = s; mg1 = g + 3; }
        s = SC(cc.x, cc.y); if (s < ms2) { ms2 = s; mg2 = g + 4; }
        s = SC(cc.z, cc.w); if (s < ms2) { ms2 = s; mg2 = g + 5; }
        s = SC(cd.x, cd.y); if (s < ms3) { ms3 = s; mg3 = g + 6; }
        s = SC(cd.z, cd.w); if (s < ms3) { ms3 = s; mg3 = g + 7; }
    }
    for (; g + 2 <= G; g += 2) {
        const float4 ca = ctr2[g >> 1];
        float s;
        s = SC(ca.x, ca.y); if (s < ms0) { ms0 = s; mg0 = g; }
        s = SC(ca.z, ca.w); if (s < ms0) { ms0 = s; mg0 = g + 1; }
    }
    if (g < G) {
        const float2 c = ctr[g];
        const float s = SC(c.x, c.y);
        if (s < ms0) { ms0 = s; mg0 = g; }
    }
    float min_score = ms0; int min_g = mg0;   // lexicographic == sequential strict-<
    if (ms1 < min_score || (ms1 == min_score && mg1 < min_g)) { min_score = ms1; min_g = mg1; }
    if (ms2 < min_score || (ms2 == min_score && mg2 < min_g)) { min_score = ms2; min_g = mg2; }
    if (ms3 < min_score || (ms3 == min_score && mg3 < min_g)) { min_score = ms3; min_g = mg3; }

    // --- phase 2: heavy loop: hit test; green -> hit bit + best; gray -> mask ---
    unsigned hm0 = 0u, hm1 = 0u, hm2 = 0u, hm3 = 0u;   // green-hit bits (compacted idx)
    unsigned gm0 = 0u, gm1 = 0u, gm2 = 0u;             // gray label bits
    float best_score = 0.f; int best_g = 0;
    for (int i = 0; i < ncomp; ++i) {
        const unsigned e = clist[i];
        const int gg = (int)(e & 0xFFu);
        const float4 A = boxA[gg];
        const float d1 = px - A.x, d2 = py - A.y, d3 = A.z - px, d4 = A.w - py;
        if (fminf(fminf(d1, d2), fminf(d3, d4)) >= 0.0f) {
            const int label = (int)((e >> 8) & 0x7Fu);
            if (e & 0x80000000u) {               // gray
                if (label < 32)      gm0 |= 1u << label;
                else if (label < 64) gm1 |= 1u << (label - 32);
                else                 gm2 |= 1u << (label - 64);
            } else {                              // green: record hit bit i
                if (i < 32)       hm0 |= 1u << i;
                else if (i < 64)  hm1 |= 1u << (i - 32);
                else if (i < 96)  hm2 |= 1u << (i - 64);
                else              hm3 |= 1u << (i - 96);
                const float2 c = ctr[gg];
                const float s = SC(c.x, c.y);
                if (s > best_score) { best_score = s; best_g = gg; }
            }
        }
    }

    // --- phase 3: owner writes its 68 B row-block ---
    const int sel = (best_score > 0.f) ? best_g : min_g;
    const float4 A = boxA[sel];
    unsigned* my = rowd + tid * RSTRIDE;
    my[0] = hm0; my[1] = hm1; my[2] = hm2; my[3] = hm3;
    my[4] = gm0; my[5] = gm1; my[6] = gm2;
    my[7] = __float_as_uint(px);
    my[8] = __float_as_uint(py);
    my[9] = __float_as_uint(inv_half);
    my[10] = __float_as_uint((px - A.x) * inv_up);
    my[11] = __float_as_uint((py - A.y) * inv_up);
    my[12] = __float_as_uint((A.z - px) * inv_up);
    my[13] = __float_as_uint((A.w - py) * inv_up);
    // single-wave block: in-order LDS ops + compiler lgkmcnt => visible below

    // --- phase 4: writeback, every byte written exactly once ---
    float4* out4 = (float4*)(out + ((size_t)b * P + (size_t)blockIdx.x * 64) * ROWF);
#pragma unroll
    for (int k = 0; k < 21; ++k) {
        const int j = k * 64 + tid;
        const unsigned r = (unsigned)j / 21u;       // magic-mul
        const int s = j - 21 * (int)r;
        const unsigned* rb = rowd + r * RSTRIDE;
        float4 v;
        if (s == 20) {
            v = make_float4(__uint_as_float(rb[10]), __uint_as_float(rb[11]),
                            __uint_as_float(rb[12]), __uint_as_float(rb[13]));
        } else {
            const int cbase = 4 * s;
            const float px_r = __uint_as_float(rb[7]);
            const float py_r = __uint_as_float(rb[8]);
            const float ih_r = __uint_as_float(rb[9]);
            float v0 = 0.f, v1 = 0.f, v2 = 0.f, v3 = 0.f;
#pragma unroll
            for (int w = 0; w < 4; ++w) {
                unsigned m = rb[w];
                while (m) {
                    const int bit = __ffs(m) - 1; m &= m - 1u;
                    const unsigned e = clist[w * 32 + bit];
                    const unsigned lab = (e >> 8) & 0x7Fu;
                    if ((int)(lab >> 2) == s) {
                        const float2 c = ctr[e & 0xFFu];
                        const float sc = rsqrtf(fmaxf(fabsf(px_r - c.x) * ih_r, 1.0f) *
                                                fmaxf(fabsf(py_r - c.y) * ih_r, 1.0f));
                        const unsigned l2 = lab & 3u;
                        v0 = (l2 == 0u) ? fmaxf(v0, sc) : v0;
                        v1 = (l2 == 1u) ? fmaxf(v1, sc) : v1;
                        v2 = (l2 == 2u) ? fmaxf(v2, sc) : v2;
                        v3 = (l2 == 3u) ? fmaxf(v3, sc) : v3;
                    }
                }
            }
            const unsigned gw = rb[4 + (s >> 3)];
            const int sh = cbase & 31;
            v0 = ((gw >> (sh + 0)) & 1u) ? -1.0f : v0;
            v1 = ((gw >> (sh + 1)) & 1u) ? -1.0f : v1;
            v2 = ((gw >> (sh + 2)) & 1u) ? -1.0f : v2;
            v3 = ((gw >> (sh + 3)) & 1u) ? -1.0f : v3;
            v = make_float4(v0, v1, v2, v3);
        }
        out4[j] = v;   // coalesced, fire-and-forget
    }
#undef SC
}

extern "C" void kernel_launch(void* const* d_in, const int* in_sizes, int n_in,
                              void* d_out, int out_size, void* d_ws, size_t ws_size,
                              hipStream_t stream) {
    const float* gt_bboxes   = (const float*)d_in[0];
    const int*   gt_labels   = (const int*)d_in[1];
    const float* points      = (const float*)d_in[2];
    const float* reg_ranges  = (const float*)d_in[3];
    const float* gray_ranges = (const float*)d_in[4];
    const float* strides     = (const float*)d_in[5];
    float* out = (float*)d_out;

    const int P = in_sizes[5];            // strides has P elements
    const int B = out_size / (P * ROWF);  // out is (B,P,84)
    const int G = in_sizes[1] / B;        // gt_labels is (B,G)  (G<=128 assumed)

    dim3 grid(P / 64, B);
    dim3 block(64);
    const size_t shmem = (size_t)G * sizeof(float4)               // boxA
                       + (size_t)((G + 1) & ~1) * sizeof(float2)  // ctr
                       + (size_t)G * sizeof(unsigned)             // clist
                       + (size_t)(64 * RSTRIDE) * sizeof(unsigned); // row-blocks
    lfd_kernel<<<grid, block, shmem, stream>>>(
        gt_bboxes, gt_labels, points, reg_ranges, gray_ranges, strides, out, G, P);
}

// Round 7
// 76.250 us; speedup vs baseline: 1.1256x; 1.1256x over previous
//
#include <hip/hip_runtime.h>

#define ROWF 84        // floats per output row (80 cls + 4 reg)
#define SENT 0xFFFFFFFFu

// One block = 256 consecutive points (4 waves) of one image. Level cumsums
// (16384,20480,21504,21760,21824) are 256-aligned except the end: last block
// has 64 valid L4 points (clamped loads, masked stores) -> block level-uniform.
//
// Design: zero post-store waits. Each thread's full 80-class row lives in
// REGISTERS (acc[80], statically indexed: unrolled init/store, and the merge
// uses an 80-case switch on a readfirstlane'd SCALAR label -- valid because
// every lane processes the same compacted gt entry). Output written once,
// fire-and-forget; wave retires on compute time.
__global__ __launch_bounds__(256) void lfd_kernel(
    const float* __restrict__ gt_bboxes,   // (B,G,4) x0,y0,w,h
    const int*   __restrict__ gt_labels,   // (B,G)
    const float* __restrict__ points,      // (P,2)
    const float* __restrict__ reg_ranges,  // (P,2)
    const float* __restrict__ gray_ranges, // (P,2)
    const float* __restrict__ strides,     // (P,)
    float* __restrict__ out,               // (B,P,84)
    int G, int P)
{
    __shared__ float4   boxA[128];    // x0,y0,x1m1,y1m1
    __shared__ float4   ctrq[64];     // cx,cy pairs (float4 view of float2[128])
    __shared__ unsigned clist[128];   // compacted size-relevant gts (ascending g)
    __shared__ unsigned flags[128];
    __shared__ int      s_ncomp;

    const int tid = threadIdx.x;
    const int b   = blockIdx.y;
    const int p   = blockIdx.x * 256 + tid;
    const bool active = (p < P);
    const int  pc = active ? p : (P - 1);     // clamp: same level (L4)

    // --- per-point (block-uniform level) constants ---
    const float px  = points[pc * 2 + 0];
    const float py  = points[pc * 2 + 1];
    const float lo  = reg_ranges[pc * 2 + 0];
    const float up  = reg_ranges[pc * 2 + 1];
    const float glo = gray_ranges[pc * 2 + 0];
    const float gup = gray_ranges[pc * 2 + 1];
    const float inv_half = 2.0f / strides[pc];   // strides pow2 -> exact
    const float inv_up   = 1.0f / up;

    // --- phase 0: cooperative gt preload + size classification ---
    if (tid < 128) {
        unsigned f = SENT;
        if (tid < G) {
            const float4 bb = *(const float4*)(gt_bboxes + ((size_t)b * G + tid) * 4);
            boxA[tid] = make_float4(bb.x, bb.y, bb.x + bb.z - 1.0f, bb.y + bb.w - 1.0f);
            ((float2*)ctrq)[tid] = make_float2(bb.x + 0.5f * bb.z, bb.y + 0.5f * bb.w);
            const float larger = fmaxf(bb.z, bb.w);
            const int lab = gt_labels[b * G + tid];
            const bool green = (lo <= larger) && (larger <= up);
            const bool gray  = ((glo <= larger) && (larger < lo)) ||
                               ((up < larger) && (larger <= gup));
            if (green || gray)
                f = (unsigned)tid | ((unsigned)lab << 8) | (gray ? 0x80000000u : 0u);
        }
        flags[tid] = f;
    }
    __syncthreads();   // early: only small input loads outstanding

    // wave 0 ballot-compacts (ascending-g order -> stable-sort tie semantics)
    if (tid < 64) {
        const unsigned f0 = flags[tid], f1 = flags[tid + 64];
        const bool i0 = (f0 != SENT), i1 = (f1 != SENT);
        const unsigned long long m0 = __ballot(i0);
        const unsigned long long m1 = __ballot(i1);
        const unsigned long long below = (1ull << tid) - 1ull;
        const int c0 = __popcll(m0);
        if (i0) clist[__popcll(m0 & below)] = f0;
        if (i1) clist[c0 + __popcll(m1 & below)] = f1;
        if (tid == 0) s_ncomp = c0 + __popcll(m1);
    }
    __syncthreads();   // still cheap: no bulk stores issued yet
    const int ncomp = s_ncomp;

    // --- phase 1: 4-chain branchless min-score scan (argmin fallback) ---
#define SC(X, Y) rsqrtf(fmaxf(fabsf(px - (X)) * inv_half, 1.0f) * \
                        fmaxf(fabsf(py - (Y)) * inv_half, 1.0f))
    const float4* ctr2 = (const float4*)ctrq;
    const float2* ctr  = (const float2*)ctrq;
    float ms0 = 1e30f, ms1 = 1e30f, ms2 = 1e30f, ms3 = 1e30f;
    int   mg0 = 0, mg1 = 0, mg2 = 0, mg3 = 0;
    int g = 0;
    for (; g + 8 <= G; g += 8) {
        const float4 ca = ctr2[(g >> 1) + 0];
        const float4 cb = ctr2[(g >> 1) + 1];
        const float4 cc = ctr2[(g >> 1) + 2];
        const float4 cd = ctr2[(g >> 1) + 3];
        float s;
        s = SC(ca.x, ca.y); if (s < ms0) { ms0 = s; mg0 = g + 0; }
        s = SC(ca.z, ca.w); if (s < ms0) { ms0 = s; mg0 = g + 1; }
        s = SC(cb.x, cb.y); if (s < ms1) { ms1 = s; mg1 = g + 2; }
        s = SC(cb.z, cb.w); if (s < ms1) { ms1 = s; mg1 = g + 3; }
        s = SC(cc.x, cc.y); if (s < ms2) { ms2 = s; mg2 = g + 4; }
        s = SC(cc.z, cc.w); if (s < ms2) { ms2 = s; mg2 = g + 5; }
        s = SC(cd.x, cd.y); if (s < ms3) { ms3 = s; mg3 = g + 6; }
        s = SC(cd.z, cd.w); if (s < ms3) { ms3 = s; mg3 = g + 7; }
    }
    for (; g + 2 <= G; g += 2) {
        const float4 ca = ctr2[g >> 1];
        float s;
        s = SC(ca.x, ca.y); if (s < ms0) { ms0 = s; mg0 = g; }
        s = SC(ca.z, ca.w); if (s < ms0) { ms0 = s; mg0 = g + 1; }
    }
    if (g < G) {
        const float2 c = ctr[g];
        const float s = SC(c.x, c.y);
        if (s < ms0) { ms0 = s; mg0 = g; }
    }
    float min_score = ms0; int min_g = mg0;   // lexicographic == sequential strict-<
    if (ms1 < min_score || (ms1 == min_score && mg1 < min_g)) { min_score = ms1; min_g = mg1; }
    if (ms2 < min_score || (ms2 == min_score && mg2 < min_g)) { min_score = ms2; min_g = mg2; }
    if (ms3 < min_score || (ms3 == min_score && mg3 < min_g)) { min_score = ms3; min_g = mg3; }

    // --- phase 2: compacted gts -> register row merge ---
    float acc[80];
#pragma unroll
    for (int i = 0; i < 80; ++i) acc[i] = 0.f;
    unsigned gm0 = 0u, gm1 = 0u, gm2 = 0u;    // per-lane gray label bits
    float best_score = 0.f; int best_g = 0;

    unsigned e = (ncomp > 0) ? clist[0] : 0u;
    for (int i = 0; i < ncomp; ++i) {
        const unsigned enext = (i + 1 < ncomp) ? clist[i + 1] : 0u;   // prefetch
        const unsigned eu  = (unsigned)__builtin_amdgcn_readfirstlane((int)e);  // uniform
        const int gg  = (int)(eu & 0xFFu);
        const int lab = (int)((eu >> 8) & 0x7Fu);                     // scalar
        const float4 A = boxA[gg];                                    // broadcast reads
        const float2 c = ctr[gg];
        const float d1 = px - A.x, d2 = py - A.y, d3 = A.z - px, d4 = A.w - py;
        const bool hit = fminf(fminf(d1, d2), fminf(d3, d4)) >= 0.0f;
        if (eu & 0x80000000u) {                // gray (uniform branch)
            const unsigned bit = 1u << (lab & 31);
            if (lab < 32)      gm0 |= hit ? bit : 0u;
            else if (lab < 64) gm1 |= hit ? bit : 0u;
            else               gm2 |= hit ? bit : 0u;
        } else {                               // green
            float s = SC(c.x, c.y);
            s = hit ? s : 0.0f;                // s>0 only on hit
            switch (lab) {                     // scalar label -> static acc index
#define CS(L) case L: acc[L] = fmaxf(acc[L], s); break;
            CS(0) CS(1) CS(2) CS(3) CS(4) CS(5) CS(6) CS(7) CS(8) CS(9)
            CS(10) CS(11) CS(12) CS(13) CS(14) CS(15) CS(16) CS(17) CS(18) CS(19)
            CS(20) CS(21) CS(22) CS(23) CS(24) CS(25) CS(26) CS(27) CS(28) CS(29)
            CS(30) CS(31) CS(32) CS(33) CS(34) CS(35) CS(36) CS(37) CS(38) CS(39)
            CS(40) CS(41) CS(42) CS(43) CS(44) CS(45) CS(46) CS(47) CS(48) CS(49)
            CS(50) CS(51) CS(52) CS(53) CS(54) CS(55) CS(56) CS(57) CS(58) CS(59)
            CS(60) CS(61) CS(62) CS(63) CS(64) CS(65) CS(66) CS(67) CS(68) CS(69)
            CS(70) CS(71) CS(72) CS(73) CS(74) CS(75) CS(76) CS(77) CS(78) CS(79)
#undef CS
            }
            if (s > best_score) { best_score = s; best_g = gg; }  // strict > => smallest g
        }
        e = enext;
    }

    // --- phase 3: write final row, every byte exactly once, fire-and-forget ---
    if (active) {
        const int sel = (best_score > 0.f) ? best_g : min_g;
        const float4 A = boxA[sel];
        float4* out4 = (float4*)(out + ((size_t)b * P + p) * ROWF);
#pragma unroll
        for (int k = 0; k < 20; ++k) {
            const unsigned gw = (k < 8) ? gm0 : ((k < 16) ? gm1 : gm2);
            const int sh = (4 * k) & 31;
            float4 v;
            v.x = ((gw >> (sh + 0)) & 1u) ? -1.0f : acc[4 * k + 0];
            v.y = ((gw >> (sh + 1)) & 1u) ? -1.0f : acc[4 * k + 1];
            v.z = ((gw >> (sh + 2)) & 1u) ? -1.0f : acc[4 * k + 2];
            v.w = ((gw >> (sh + 3)) & 1u) ? -1.0f : acc[4 * k + 3];
            out4[k] = v;
        }
        out4[20] = make_float4((px - A.x) * inv_up, (py - A.y) * inv_up,
                               (A.z - px) * inv_up, (A.w - py) * inv_up);
    }
#undef SC
}

extern "C" void kernel_launch(void* const* d_in, const int* in_sizes, int n_in,
                              void* d_out, int out_size, void* d_ws, size_t ws_size,
                              hipStream_t stream) {
    const float* gt_bboxes   = (const float*)d_in[0];
    const int*   gt_labels   = (const int*)d_in[1];
    const float* points      = (const float*)d_in[2];
    const float* reg_ranges  = (const float*)d_in[3];
    const float* gray_ranges = (const float*)d_in[4];
    const float* strides     = (const float*)d_in[5];
    float* out = (float*)d_out;

    const int P = in_sizes[5];            // strides has P elements
    const int B = out_size / (P * ROWF);  // out is (B,P,84)
    const int G = in_sizes[1] / B;        // gt_labels is (B,G)  (G<=128 assumed)

    dim3 grid((P + 255) / 256, B);
    dim3 block(256);
    lfd_kernel<<<grid, block, 0, stream>>>(
        gt_bboxes, gt_labels, points, reg_ranges, gray_ranges, strides, out, G, P);
}

// Round 8
// 48.841 us; speedup vs baseline: 1.7572x; 1.5612x over previous
//
#include <hip/hip_runtime.h>

#define ROWF 84        // floats per output row (80 cls + 4 reg)
#define KSLOT 8        // per-thread green-label register slots

// One block = one wave = 64 consecutive points of one image (levels are
// 64-aligned; P = 341*64 exactly, no tail). No barriers anywhere.
//
//  entry  : 21 coalesced float4 zero-stores of the block's whole output
//           region (fire-and-forget; acks return during phases 0-2)
//  phase 0: preload gts -> LDS, classify size; ballot-compact into SEPARATE
//           green and gray lists (ascending g -> stable-sort tie semantics)
//  phase 1: 4-chain branchless min-score scan over ALL gts (argmin fallback)
//  phase 1b: gray loop (register bitmask only -- more fence cover)
//  FENCE1 (vmcnt 0): zeros acked; latency hidden under 0/1/1b
//  phase 2: green loop: hit -> score -> 8-slot register max-merge (static
//           indexed); rare spill (>8 distinct labels) -> atomicMax + FENCE2
//  phase 3: patch stores, all to DISTINCT own-row addresses: slot values
//           (skipping gray-masked labels), gray -1s, reg float4. Fire-and-
//           forget; wave retires into the store queue.
__global__ __launch_bounds__(64) void lfd_kernel(
    const float* __restrict__ gt_bboxes,   // (B,G,4) x0,y0,w,h
    const int*   __restrict__ gt_labels,   // (B,G)
    const float* __restrict__ points,      // (P,2)
    const float* __restrict__ reg_ranges,  // (P,2)
    const float* __restrict__ gray_ranges, // (P,2)
    const float* __restrict__ strides,     // (P,)
    float* __restrict__ out,               // (B,P,84)
    int G, int P)
{
    __shared__ float4   boxA[128];   // x0,y0,x1m1,y1m1
    __shared__ float4   ctrq[64];    // cx,cy pairs (float4 view of float2[128])
    __shared__ unsigned glist[128];  // compacted green gts (ascending g)
    __shared__ unsigned rlist[128];  // compacted gray  gts

    const int tid = threadIdx.x;
    const int b   = blockIdx.y;
    const int p   = blockIdx.x * 64 + tid;

    // --- entry: coalesced zeros of the block's output region ---
    float4* blk4 = (float4*)(out + ((size_t)b * P + (size_t)blockIdx.x * 64) * ROWF);
    const float4 z = make_float4(0.f, 0.f, 0.f, 0.f);
#pragma unroll
    for (int k = 0; k < 21; ++k)
        blk4[k * 64 + tid] = z;          // 1344 float4, fully coalesced

    // --- per-point (wave-uniform level) constants ---
    const float px  = points[p * 2 + 0];
    const float py  = points[p * 2 + 1];
    const float lo  = reg_ranges[p * 2 + 0];
    const float up  = reg_ranges[p * 2 + 1];
    const float glo = gray_ranges[p * 2 + 0];
    const float gup = gray_ranges[p * 2 + 1];
    const float inv_half = 2.0f / strides[p];   // strides pow2 -> exact
    const float inv_up   = 1.0f / up;

    // --- phase 0: preload gts (slots g=tid, g=tid+64), classify ---
    bool gr0 = false, gy0 = false, gr1 = false, gy1 = false;
    int  lab0 = 0, lab1 = 0;
    {
        int g = tid;
        if (g < G) {
            const float4 bb = *(const float4*)(gt_bboxes + (size_t)(b * G + g) * 4);
            boxA[g] = make_float4(bb.x, bb.y, bb.x + bb.z - 1.0f, bb.y + bb.w - 1.0f);
            ((float2*)ctrq)[g] = make_float2(bb.x + 0.5f * bb.z, bb.y + 0.5f * bb.w);
            const float larger = fmaxf(bb.z, bb.w);
            lab0 = gt_labels[b * G + g];
            gr0 = (lo <= larger) && (larger <= up);
            gy0 = ((glo <= larger) && (larger < lo)) || ((up < larger) && (larger <= gup));
        }
        g = tid + 64;
        if (g < G) {
            const float4 bb = *(const float4*)(gt_bboxes + (size_t)(b * G + g) * 4);
            boxA[g] = make_float4(bb.x, bb.y, bb.x + bb.z - 1.0f, bb.y + bb.w - 1.0f);
            ((float2*)ctrq)[g] = make_float2(bb.x + 0.5f * bb.z, bb.y + 0.5f * bb.w);
            const float larger = fmaxf(bb.z, bb.w);
            lab1 = gt_labels[b * G + g];
            gr1 = (lo <= larger) && (larger <= up);
            gy1 = ((glo <= larger) && (larger < lo)) || ((up < larger) && (larger <= gup));
        }
    }
    // two ballot-compactions (single wave; ascending-g order preserved)
    const unsigned long long bg0 = __ballot(gr0);
    const unsigned long long bg1 = __ballot(gr1);
    const unsigned long long br0 = __ballot(gy0);
    const unsigned long long br1 = __ballot(gy1);
    const unsigned long long below = (1ull << tid) - 1ull;
    if (gr0) glist[__popcll(bg0 & below)] = (unsigned)tid | ((unsigned)lab0 << 8);
    if (gr1) glist[__popcll(bg0) + __popcll(bg1 & below)] =
        (unsigned)(tid + 64) | ((unsigned)lab1 << 8);
    const int ng = __popcll(bg0) + __popcll(bg1);
    if (gy0) rlist[__popcll(br0 & below)] = (unsigned)tid | ((unsigned)lab0 << 8);
    if (gy1) rlist[__popcll(br0) + __popcll(br1 & below)] =
        (unsigned)(tid + 64) | ((unsigned)lab1 << 8);
    const int nr = __popcll(br0) + __popcll(br1);

    // --- phase 1: 4-chain branchless min-score scan (argmin fallback) ---
#define SC(X, Y) rsqrtf(fmaxf(fabsf(px - (X)) * inv_half, 1.0f) * \
                        fmaxf(fabsf(py - (Y)) * inv_half, 1.0f))
    const float4* ctr2 = (const float4*)ctrq;
    const float2* ctr  = (const float2*)ctrq;
    float ms0 = 1e30f, ms1 = 1e30f, ms2 = 1e30f, ms3 = 1e30f;
    int   mg0 = 0, mg1 = 0, mg2 = 0, mg3 = 0;
    int g = 0;
    for (; g + 8 <= G; g += 8) {
        const float4 ca = ctr2[(g >> 1) + 0];
        const float4 cb = ctr2[(g >> 1) + 1];
        const float4 cc = ctr2[(g >> 1) + 2];
        const float4 cd = ctr2[(g >> 1) + 3];
        float s;
        s = SC(ca.x, ca.y); if (s < ms0) { ms0 = s; mg0 = g + 0; }
        s = SC(ca.z, ca.w); if (s < ms0) { ms0 = s; mg0 = g + 1; }
        s = SC(cb.x, cb.y); if (s < ms1) { ms1 = s; mg1 = g + 2; }
        s = SC(cb.z, cb.w); if (s < ms1) { ms1 = s; mg1 = g + 3; }
        s = SC(cc.x, cc.y); if (s < ms2) { ms2 = s; mg2 = g + 4; }
        s = SC(cc.z, cc.w); if (s < ms2) { ms2 = s; mg2 = g + 5; }
        s = SC(cd.x, cd.y); if (s < ms3) { ms3 = s; mg3 = g + 6; }
        s = SC(cd.z, cd.w); if (s < ms3) { ms3 = s; mg3 = g + 7; }
    }
    for (; g + 2 <= G; g += 2) {
        const float4 ca = ctr2[g >> 1];
        float s;
        s = SC(ca.x, ca.y); if (s < ms0) { ms0 = s; mg0 = g; }
        s = SC(ca.z, ca.w); if (s < ms0) { ms0 = s; mg0 = g + 1; }
    }
    if (g < G) {
        const float2 c = ctr[g];
        const float s = SC(c.x, c.y);
        if (s < ms0) { ms0 = s; mg0 = g; }
    }
    float min_score = ms0; int min_g = mg0;   // lexicographic == sequential strict-<
    if (ms1 < min_score || (ms1 == min_score && mg1 < min_g)) { min_score = ms1; min_g = mg1; }
    if (ms2 < min_score || (ms2 == min_score && mg2 < min_g)) { min_score = ms2; min_g = mg2; }
    if (ms3 < min_score || (ms3 == min_score && mg3 < min_g)) { min_score = ms3; min_g = mg3; }

    // --- phase 1b: gray loop (register bitmask only; no stores) ---
    unsigned gm0 = 0u, gm1 = 0u, gm2 = 0u;
    for (int i = 0; i < nr; ++i) {
        const unsigned e = rlist[i];
        const int gg = (int)(e & 0xFFu);
        const float4 A = boxA[gg];
        const float d1 = px - A.x, d2 = py - A.y, d3 = A.z - px, d4 = A.w - py;
        if (fminf(fminf(d1, d2), fminf(d3, d4)) >= 0.0f) {
            const int lab = (int)(e >> 8);
            if (lab < 32)      gm0 |= 1u << lab;
            else if (lab < 64) gm1 |= 1u << (lab - 32);
            else               gm2 |= 1u << (lab - 64);
        }
    }

    // FENCE1: zero-stores acked (latency covered by phases 0/1/1b)
    asm volatile("s_waitcnt vmcnt(0)" ::: "memory");

    // --- phase 2: green loop: slot merge in registers; rare spill -> atomic ---
    float* myout = out + ((size_t)b * P + p) * ROWF;
    int   slab[KSLOT];
    float sval[KSLOT];
#pragma unroll
    for (int j = 0; j < KSLOT; ++j) { slab[j] = -1; sval[j] = 0.f; }
    int cnt = 0; bool spill = false;
    float best_score = 0.f; int best_g = 0;

    for (int i = 0; i < ng; ++i) {
        const unsigned e = glist[i];
        const int gg = (int)(e & 0xFFu);
        const float4 A = boxA[gg];
        const float d1 = px - A.x, d2 = py - A.y, d3 = A.z - px, d4 = A.w - py;
        if (fminf(fminf(d1, d2), fminf(d3, d4)) >= 0.0f) {
            const int lab = (int)(e >> 8);
            const float2 c = ctr[gg];
            const float s = SC(c.x, c.y);          // s in (0,1]
            bool placed = false;
#pragma unroll
            for (int j = 0; j < KSLOT; ++j)
                if (slab[j] == lab) { sval[j] = fmaxf(sval[j], s); placed = true; }
            if (!placed) {
                if (cnt < KSLOT) {
#pragma unroll
                    for (int j = 0; j < KSLOT; ++j)
                        if (cnt == j) { slab[j] = lab; sval[j] = s; }
                    ++cnt;
                } else {
                    spill = true;                  // >8 distinct green labels
                    atomicMax((int*)(myout + lab), __float_as_int(s));
                }
            }
            if (s > best_score) { best_score = s; best_g = gg; }  // strict > => smallest g
        }
    }
    if (__any(spill))   // spill atomics must land before gray -1 overrides
        asm volatile("s_waitcnt vmcnt(0)" ::: "memory");

    // --- phase 3: patch stores, all distinct own-row addresses ---
#pragma unroll
    for (int j = 0; j < KSLOT; ++j) {
        if (j < cnt) {
            const int L = slab[j];
            const unsigned gmask = (L < 32) ? gm0 : ((L < 64) ? gm1 : gm2);
            if (!((gmask >> (L & 31)) & 1u))      // gray wins -> skip green store
                myout[L] = sval[j];
        }
    }
    unsigned t;
    t = gm0; while (t) { const int c = __ffs(t) - 1; myout[c]      = -1.0f; t &= t - 1u; }
    t = gm1; while (t) { const int c = __ffs(t) - 1; myout[32 + c] = -1.0f; t &= t - 1u; }
    t = gm2; while (t) { const int c = __ffs(t) - 1; myout[64 + c] = -1.0f; t &= t - 1u; }

    const int sel = (best_score > 0.f) ? best_g : min_g;
    const float4 A = boxA[sel];
    *(float4*)(myout + 80) = make_float4((px - A.x) * inv_up, (py - A.y) * inv_up,
                                         (A.z - px) * inv_up, (A.w - py) * inv_up);
#undef SC
}

extern "C" void kernel_launch(void* const* d_in, const int* in_sizes, int n_in,
                              void* d_out, int out_size, void* d_ws, size_t ws_size,
                              hipStream_t stream) {
    const float* gt_bboxes   = (const float*)d_in[0];
    const int*   gt_labels   = (const int*)d_in[1];
    const float* points      = (const float*)d_in[2];
    const float* reg_ranges  = (const float*)d_in[3];
    const float* gray_ranges = (const float*)d_in[4];
    const float* strides     = (const float*)d_in[5];
    float* out = (float*)d_out;

    const int P = in_sizes[5];            // strides has P elements
    const int B = out_size / (P * ROWF);  // out is (B,P,84)
    const int G = in_sizes[1] / B;        // gt_labels is (B,G)  (G<=128 assumed)

    dim3 grid(P / 64, B);
    dim3 block(64);
    lfd_kernel<<<grid, block, 0, stream>>>(
        gt_bboxes, gt_labels, points, reg_ranges, gray_ranges, strides, out, G, P);
}

// Round 10
// 35.671 us; speedup vs baseline: 2.4060x; 1.3692x over previous
//
#include <hip/hip_runtime.h>

#define ROWF 84        // floats per output row (80 cls + 4 reg)

typedef float f32x4 __attribute__((ext_vector_type(4)));   // native vector for nt-store

// One block = one wave = 64 consecutive points of one image (levels are
// 64-aligned so the wave is level-uniform).
//  Phase 0: preload gt boxes into LDS; ballot-compact size-relevant gts
//           (ascending-g order preserved -> stable-sort tie semantics).
//  Phase 1: bulk-zero this block's 64x84-float output region with
//           NON-TEMPORAL coalesced float4 stores (bypass L2/MALL
//           write-allocate -> drain at streaming rate).
//  Phase 2: branchless min-score scan over ALL gts (argmin fallback),
//           overlapping the zero-store drain.
//  fence vmcnt(0)
//  Phase 3: per compacted gt: hit test; green -> atomicMax(out[p][label])
//           (positive-float bits, commutative) + best-green tracking.
//  fence vmcnt(0)
//  Phase 4: gray -1 overrides (plain stores), reg float4 store. All patches
//           to row p come from thread p only -> no cross-thread hazards.
__global__ __launch_bounds__(64) void lfd_assign_kernel(
    const float* __restrict__ gt_bboxes,   // (B,G,4) x0,y0,w,h
    const int*   __restrict__ gt_labels,   // (B,G)
    const float* __restrict__ points,      // (P,2)
    const float* __restrict__ reg_ranges,  // (P,2)
    const float* __restrict__ gray_ranges, // (P,2)
    const float* __restrict__ strides,     // (P,)
    float* __restrict__ out,               // (B,P,84)
    int G, int P)
{
    extern __shared__ float lds[];
    float4*   boxA  = (float4*)lds;                      // [G] x0,y0,x1m1,y1m1
    float2*   ctr   = (float2*)(boxA + G);               // [G] cx,cy
    unsigned* clist = (unsigned*)(ctr + ((G + 1) & ~1)); // [G] compacted

    const int tid = threadIdx.x;
    const int b   = blockIdx.y;
    const int p   = blockIdx.x * 64 + tid;

    // --- per-point (wave-uniform level) constants ---
    const float px  = points[p * 2 + 0];
    const float py  = points[p * 2 + 1];
    const float lo  = reg_ranges[p * 2 + 0];
    const float up  = reg_ranges[p * 2 + 1];
    const float glo = gray_ranges[p * 2 + 0];
    const float gup = gray_ranges[p * 2 + 1];
    const float inv_half = 2.0f / strides[p];  // strides pow2 -> exact
    const float inv_up   = 1.0f / up;

    // --- phase 0: preload gts (slots g=tid, g=tid+64), classify ---
    bool i0 = false, gray0 = false, i1 = false, gray1 = false;
    int  lab0 = 0, lab1 = 0;
    {
        int g = tid;
        if (g < G) {
            const float4 bb = *(const float4*)(gt_bboxes + (size_t)(b * G + g) * 4);
            boxA[g] = make_float4(bb.x, bb.y, bb.x + bb.z - 1.0f, bb.y + bb.w - 1.0f);
            ctr[g]  = make_float2(bb.x + 0.5f * bb.z, bb.y + 0.5f * bb.w);
            const float larger = fmaxf(bb.z, bb.w);
            lab0 = gt_labels[b * G + g];
            const bool green = (lo <= larger) && (larger <= up);
            gray0 = ((glo <= larger) && (larger < lo)) || ((up < larger) && (larger <= gup));
            i0 = green || gray0;
        }
        g = tid + 64;
        if (g < G) {
            const float4 bb = *(const float4*)(gt_bboxes + (size_t)(b * G + g) * 4);
            boxA[g] = make_float4(bb.x, bb.y, bb.x + bb.z - 1.0f, bb.y + bb.w - 1.0f);
            ctr[g]  = make_float2(bb.x + 0.5f * bb.z, bb.y + 0.5f * bb.w);
            const float larger = fmaxf(bb.z, bb.w);
            lab1 = gt_labels[b * G + g];
            const bool green = (lo <= larger) && (larger <= up);
            gray1 = ((glo <= larger) && (larger < lo)) || ((up < larger) && (larger <= gup));
            i1 = green || gray1;
        }
    }
    // ballot-compaction (single wave; ascending-g order preserved)
    const unsigned long long m0 = __ballot(i0);
    const unsigned long long m1 = __ballot(i1);
    const int c0 = __popcll(m0);
    const unsigned long long below = (1ull << tid) - 1ull;
    if (i0) clist[__popcll(m0 & below)] =
        (unsigned)tid | ((unsigned)lab0 << 8) | (gray0 ? 0x80000000u : 0u);
    if (i1) clist[c0 + __popcll(m1 & below)] =
        (unsigned)(tid + 64) | ((unsigned)lab1 << 8) | (gray1 ? 0x80000000u : 0u);
    const int ncomp = c0 + __popcll(m1);

    // --- phase 1: bulk-zero the block's output region (non-temporal) ---
    f32x4* dst4 = (f32x4*)(out + (size_t)(b * P + blockIdx.x * 64) * ROWF);
    const f32x4 z4 = (f32x4){0.f, 0.f, 0.f, 0.f};
#pragma unroll
    for (int k = 0; k < 21; ++k)
        __builtin_nontemporal_store(z4, dst4 + k * 64 + tid);

    // --- phase 2: branchless min-score scan over ALL gts (2 per b128) ---
    const float4* ctr2 = (const float4*)ctr;
    float min_score = 1e30f; int min_g = 0;
    int g = 0;
#pragma unroll 4
    for (; g + 1 < G; g += 2) {
        const float4 c = ctr2[g >> 1];
        const float s0 = rsqrtf(fmaxf(fabsf(px - c.x) * inv_half, 1.0f) *
                                fmaxf(fabsf(py - c.y) * inv_half, 1.0f));
        const float s1 = rsqrtf(fmaxf(fabsf(px - c.z) * inv_half, 1.0f) *
                                fmaxf(fabsf(py - c.w) * inv_half, 1.0f));
        if (s0 < min_score) { min_score = s0; min_g = g; }
        if (s1 < min_score) { min_score = s1; min_g = g + 1; }
    }
    if (g < G) {
        const float2 c = ctr[g];
        const float s0 = rsqrtf(fmaxf(fabsf(px - c.x) * inv_half, 1.0f) *
                                fmaxf(fabsf(py - c.y) * inv_half, 1.0f));
        if (s0 < min_score) { min_score = s0; min_g = g; }
    }

    // zeros must be complete before any same-address atomic/patch
    asm volatile("s_waitcnt vmcnt(0)" ::: "memory");

    // --- phase 3: compacted gts: hit test, green atomicMax + best ---
    float* myout = out + (size_t)(b * P + p) * ROWF;
    float best_score = 0.0f; int best_g = 0;
    unsigned gm0 = 0u, gm1 = 0u, gm2 = 0u;
    for (int i = 0; i < ncomp; ++i) {
        const unsigned e = clist[i];
        const int gg = (int)(e & 0xFFu);
        const float4 A = boxA[gg];
        const float d1 = px - A.x, d2 = py - A.y, d3 = A.z - px, d4 = A.w - py;
        if (fminf(fminf(d1, d2), fminf(d3, d4)) >= 0.0f) {
            const int label = (int)((e >> 8) & 0x7Fu);
            if (e & 0x80000000u) {               // gray
                if (label < 32)      gm0 |= 1u << label;
                else if (label < 64) gm1 |= 1u << (label - 32);
                else                 gm2 |= 1u << (label - 64);
            } else {                              // green
                const float2 c = ctr[gg];
                const float s = rsqrtf(fmaxf(fabsf(px - c.x) * inv_half, 1.0f) *
                                       fmaxf(fabsf(py - c.y) * inv_half, 1.0f));
                // zeros landed; s>0 so int order == float order
                atomicMax((int*)(myout + label), __float_as_int(s));
                if (s > best_score) { best_score = s; best_g = gg; }
            }
        }
    }

    // own atomics must land before own gray -1 stores (same addresses)
    asm volatile("s_waitcnt vmcnt(0)" ::: "memory");

    // --- phase 4: gray overrides + reg store (row p touched only by thread p) ---
    unsigned t;
    t = gm0; while (t) { const int c = __ffs(t) - 1; myout[c]      = -1.0f; t &= t - 1u; }
    t = gm1; while (t) { const int c = __ffs(t) - 1; myout[32 + c] = -1.0f; t &= t - 1u; }
    t = gm2; while (t) { const int c = __ffs(t) - 1; myout[64 + c] = -1.0f; t &= t - 1u; }

    const int sel = (best_score > 0.0f) ? best_g : min_g;
    const float4 A = boxA[sel];
    *(float4*)(myout + 80) = make_float4((px - A.x) * inv_up, (py - A.y) * inv_up,
                                         (A.z - px) * inv_up, (A.w - py) * inv_up);
}

extern "C" void kernel_launch(void* const* d_in, const int* in_sizes, int n_in,
                              void* d_out, int out_size, void* d_ws, size_t ws_size,
                              hipStream_t stream) {
    const float* gt_bboxes   = (const float*)d_in[0];
    const int*   gt_labels   = (const int*)d_in[1];
    const float* points      = (const float*)d_in[2];
    const float* reg_ranges  = (const float*)d_in[3];
    const float* gray_ranges = (const float*)d_in[4];
    const float* strides     = (const float*)d_in[5];
    float* out = (float*)d_out;

    const int P = in_sizes[5];            // strides has P elements
    const int B = out_size / (P * ROWF);  // out is (B,P,84)
    const int G = in_sizes[1] / B;        // gt_labels is (B,G)  (G<=128 assumed)

    dim3 grid(P / 64, B);
    dim3 block(64);
    const size_t shmem = (size_t)G * sizeof(float4)               // boxA
                       + (size_t)((G + 1) & ~1) * sizeof(float2)  // ctr
                       + (size_t)G * sizeof(unsigned);            // clist
    lfd_assign_kernel<<<grid, block, shmem, stream>>>(
        gt_bboxes, gt_labels, points, reg_ranges, gray_ranges, strides, out, G, P);
}